// Round 22
// baseline (2555.925 us; speedup 1.0000x reference)
//
#include <hip/hip_runtime.h>

typedef _Float16 half8 __attribute__((ext_vector_type(8)));
typedef float floatx4 __attribute__((ext_vector_type(4)));
typedef unsigned long long u64t;

#define B_ 64
#define S_ 512
#define H_ 1024

// Advisory slots, padded to one 64B line each (r17-proven). .bss. Monotonic:
// +S_ per launch. e0 = own slot read before any arrival. Slot = "payload
// ISSUED" (no drain behind it); per-word tags carry the actual validity.
__device__ unsigned slotP[4][64][16];

__device__ __forceinline__ float sigmoidf_(float x) { return 1.0f / (1.0f + __expf(-x)); }
__device__ __forceinline__ float tanhf_(float x) {
    return 1.0f - 2.0f / (__expf(2.0f * x) + 1.0f);
}

// 256 blocks x 256 threads -- r21 base (1.555 ms) with the publisher DRAIN
// LEG REMOVED. Publish: tagged stores (fire) -> __syncthreads (issue order
// across waves) -> tid0 slot store. No s_waitcnt vmcnt(0) on the publish
// path (was ~0.45us/step of serialized LLC ack).
//
// Payload word = 8B atom {u16 tag | 3x f16}: 8B aligned stores/loads are
// atomic, so each word self-validates -- slot may overtake payload in
// flight; consumer then re-bursts (rare; bounded by tags). Single-read
// discipline preserved (burst fires once after the advisory gate) -- the
// r12/r19 failure was continuous re-bursting, not tag bytes.
// Row packing: per 8-col chunk, 3 words {c0,c1,c2}{c3,c4,c5}{c6,c7,pad};
// row stride 128 chunks x 3 words. pub = 2 x 64 x 384 u64 = 384 KB.
//
// 16-bit tag safety: tags advance 512/launch; every word rewritten every
// launch => leftovers exactly 1 launch old; collision needs step>512 --
// impossible. ws poison 0xAAAA can't match (slot gate + tag both).
// WAR safety: X publishes buf[(t+1)&1] only after X's reduce-sync joined
// all 4 waves' TAG-VALIDATED step-t reads; validated read of P's tag-t word
// happens-after P's publish(t), which happens-after P's completed step-t-1
// reads of buf[(t-1)&1] == buf[(t+1)&1]. Causality via observed stores.
__global__ void __launch_bounds__(256, 1)
lstm_scan(const float* __restrict__ emb, const float* __restrict__ W, const float* __restrict__ bW,
          const float* __restrict__ U, const float* __restrict__ bU,
          const float* __restrict__ V, const float* __restrict__ bV,
          float* __restrict__ out, unsigned char* __restrict__ ws)
{
    const int bid  = blockIdx.x;
    const int cb   = bid & 63;    // column group (16 H-cols)
    const int mb   = bid >> 6;    // batch group (16 batches)
    const int tid  = threadIdx.x;
    const int w    = tid >> 6;    // wave id = K-quarter
    const int lane = tid & 63;
    const int fr   = lane & 15;   // A-frag row index
    const int kg   = lane >> 4;   // A-frag k-block

    u64t* pub = (u64t*)ws;        // [2][64 rows][384 words] = 384 KB

    __shared__ __align__(16) float part[2][4 * 3 * 64 * 4];   // 2 x 12 KB

    const unsigned e0 = __hip_atomic_load(&slotP[mb][cb][0], __ATOMIC_RELAXED,
                                          __HIP_MEMORY_SCOPE_AGENT);

    // ---- persistent weight fragments (f16, registers): 3 gates x 8 ksteps ----
    // B-frag: lane l holds B[k=(l>>4)*8+e][n=l&15], B[k][n]=Wgate[16cb+n][k].
    half8 Bf[3][8];
    {
        const int jrow = cb * 16 + fr;
        const int kb   = w * 256 + kg * 8;
        const float* p0 = W + jrow * H_ + kb;
        const float* p1 = U + jrow * H_ + kb;
        const float* p2 = V + jrow * H_ + kb;
        #pragma unroll
        for (int ks = 0; ks < 8; ++ks) {
            half8 h0, h1, h2;
            #pragma unroll
            for (int e = 0; e < 8; ++e) {
                h0[e] = (_Float16)p0[ks * 32 + e];
                h1[e] = (_Float16)p1[ks * 32 + e];
                h2[e] = (_Float16)p2[ks * 32 + e];
            }
            Bf[0][ks] = h0; Bf[1][ks] = h1; Bf[2][ks] = h2;
        }
    }

    // ---- elementwise ownership: thread -> ONE cell (b, j) ----
    const int rt = tid >> 4;
    const int ct = tid & 15;
    const int b  = mb * 16 + rt;
    const int j  = cb * 16 + ct;
    const float bw = bW[j], bu = bU[j], bv = bV[j];
    const int rl = (rt >> 2) * 16 + ct;   // C/D source lane (proven)
    const int rr = rt & 3;                // C/D source reg

    // publisher word role: ct in {0,3,6,8,11,14} stores {tag, col ct, ct+1, ct+2}
    const bool storer = (ct == 0) | (ct == 3) | (ct == 6) |
                        (ct == 8) | (ct == 11) | (ct == 14);
    // word address (u64 idx) within a row: chunk (2cb + (ct>>3)), word (ct&7)/3
    const unsigned rowword = (unsigned)((2 * cb + (ct >> 3)) * 3 + ((ct & 7) / 3));
    const int sl1 = (lane & 48) | ((ct + 1) & 15);   // shfl src for col ct+1
    const int sl2 = (lane & 48) | ((ct + 2) & 15);   // shfl src for col ct+2

    // publish: tagged 8B words, fire-and-forget; barrier orders issue across
    // waves; tid0 raises the advisory slot. NO vmcnt drain.
    auto publish = [&](int buf, unsigned slotval, float xin) {
        union { _Float16 h; unsigned short u; } cvp; cvp.h = (_Float16)xin;
        unsigned mine = cvp.u;
        unsigned v1 = (unsigned)__shfl((int)mine, sl1);
        unsigned v2 = (unsigned)__shfl((int)mine, sl2);
        if (storer) {
            u64t word = (u64t)(unsigned short)slotval
                      | ((u64t)(unsigned short)mine << 16)
                      | ((u64t)(unsigned short)v1 << 32)
                      | ((u64t)(unsigned short)v2 << 48);
            __hip_atomic_store(&pub[(unsigned)(buf * 64 + b) * 384 + rowword], word,
                               __ATOMIC_RELAXED, __HIP_MEMORY_SCOPE_AGENT);
        }
        __syncthreads();
        if (tid == 0)
            __hip_atomic_store(&slotP[mb][cb][0], slotval, __ATOMIC_RELAXED,
                               __HIP_MEMORY_SCOPE_AGENT);
    };

    // advisory quarter-poll (r21 verbatim): lanes<16 poll the wave's 16
    // source blocks' padded lines; __all exits the wave together.
    auto waitq = [&](unsigned tgt) {
        for (;;) {
            unsigned v = tgt;
            if (lane < 16)
                v = __hip_atomic_load(&slotP[mb][w * 16 + lane][0], __ATOMIC_RELAXED,
                                      __HIP_MEMORY_SCOPE_AGENT);
            if (__all((int)(v - tgt) >= 0)) break;
            __builtin_amdgcn_s_sleep(4);
        }
        asm volatile("" ::: "memory");
    };

    float p1s = 0.0f;
    float xio = emb[(b * S_ + 0) * H_ + j];    // p2 init = 0
    publish(0, e0 + 1u, xio);
    float embn = emb[(b * S_ + 1) * H_ + j];   // prefetch t=1 (compiler-managed)

    for (int t = 0; t < S_; ++t) {
        waitq(e0 + (unsigned)t + 1u);
        const unsigned short tag16 = (unsigned short)(e0 + (unsigned)t + 1u);

        // ---- tagged payload burst: 24 forced dwordx2 sc1 (one round-trip);
        // chunk c8 = 32w + 4ks + kg -> byte base + 96*ks + {0,8,16}.
        const char* base = (const char*)(pub
                          + ((unsigned)((t & 1) * 64 + mb * 16 + fr) * 384
                             + (unsigned)(32 * w + kg) * 3));
        u64t W00,W01,W02,W03,W04,W05,W06,W07,W08,W09,W10,W11,
             W12,W13,W14,W15,W16,W17,W18,W19,W20,W21,W22,W23;
        bool firstTry = true;
        for (;;) {
            #define LD(dst, OFF) \
                asm volatile("global_load_dwordx2 %0, %1, off offset:" #OFF " sc1" \
                             : "=v"(dst) : "v"(base));
            LD(W00,   0) LD(W01,   8) LD(W02,  16)
            LD(W03,  96) LD(W04, 104) LD(W05, 112)
            LD(W06, 192) LD(W07, 200) LD(W08, 208)
            LD(W09, 288) LD(W10, 296) LD(W11, 304)
            LD(W12, 384) LD(W13, 392) LD(W14, 400)
            LD(W15, 480) LD(W16, 488) LD(W17, 496)
            LD(W18, 576) LD(W19, 584) LD(W20, 592)
            LD(W21, 672) LD(W22, 680) LD(W23, 688)
            #undef LD
            asm volatile("s_waitcnt vmcnt(0)" ::: "memory");
            __builtin_amdgcn_sched_barrier(0);   // rule #18
            bool ok = ((unsigned short)W00 == tag16) & ((unsigned short)W01 == tag16)
                    & ((unsigned short)W02 == tag16) & ((unsigned short)W03 == tag16)
                    & ((unsigned short)W04 == tag16) & ((unsigned short)W05 == tag16)
                    & ((unsigned short)W06 == tag16) & ((unsigned short)W07 == tag16)
                    & ((unsigned short)W08 == tag16) & ((unsigned short)W09 == tag16)
                    & ((unsigned short)W10 == tag16) & ((unsigned short)W11 == tag16)
                    & ((unsigned short)W12 == tag16) & ((unsigned short)W13 == tag16)
                    & ((unsigned short)W14 == tag16) & ((unsigned short)W15 == tag16)
                    & ((unsigned short)W16 == tag16) & ((unsigned short)W17 == tag16)
                    & ((unsigned short)W18 == tag16) & ((unsigned short)W19 == tag16)
                    & ((unsigned short)W20 == tag16) & ((unsigned short)W21 == tag16)
                    & ((unsigned short)W22 == tag16) & ((unsigned short)W23 == tag16);
            if (__all(ok)) break;
            // rare: slot overtook payload in flight. Bounded backoff re-burst.
            if (firstTry) { __builtin_amdgcn_s_sleep(1); firstTry = false; }
            else          { __builtin_amdgcn_s_sleep(4); }
        }

        // ---- MFMA; extract 8 halves per ks from 3 tagged words ----
        floatx4 a0 = {0.f, 0.f, 0.f, 0.f};
        floatx4 a1 = {0.f, 0.f, 0.f, 0.f};
        floatx4 a2 = {0.f, 0.f, 0.f, 0.f};
        union { unsigned u[4]; half8 h; } cva;
        #define DO_KS(ks, Wa, Wb, Wc)                                                 \
        {                                                                             \
            cva.u[0] = (unsigned)(Wa >> 16);                                          \
            cva.u[1] = (unsigned)(Wa >> 48) | (((unsigned)(Wb >> 16) & 0xFFFFu) << 16); \
            cva.u[2] = (unsigned)(Wb >> 32);                                          \
            cva.u[3] = (unsigned)(Wc >> 16);                                          \
            half8 Af = cva.h;                                                         \
            a0 = __builtin_amdgcn_mfma_f32_16x16x32_f16(Af, Bf[0][ks], a0, 0, 0, 0);  \
            a1 = __builtin_amdgcn_mfma_f32_16x16x32_f16(Af, Bf[1][ks], a1, 0, 0, 0);  \
            a2 = __builtin_amdgcn_mfma_f32_16x16x32_f16(Af, Bf[2][ks], a2, 0, 0, 0);  \
        }
        DO_KS(0, W00, W01, W02) DO_KS(1, W03, W04, W05)
        DO_KS(2, W06, W07, W08) DO_KS(3, W09, W10, W11)
        DO_KS(4, W12, W13, W14) DO_KS(5, W15, W16, W17)
        DO_KS(6, W18, W19, W20) DO_KS(7, W21, W22, W23)
        #undef DO_KS

        // ---- K-reduction in LDS (double-buffered, one sync) ----
        float* pp = part[t & 1];
        *(floatx4*)&pp[((w * 3 + 0) * 64 + lane) * 4] = a0;
        *(floatx4*)&pp[((w * 3 + 1) * 64 + lane) * 4] = a1;
        *(floatx4*)&pp[((w * 3 + 2) * 64 + lane) * 4] = a2;
        __syncthreads();

        float pf = bw, pu = bu, pv = bv;
        #pragma unroll
        for (int wv = 0; wv < 4; ++wv) {
            pf += pp[((wv * 3 + 0) * 64 + rl) * 4 + rr];
            pu += pp[((wv * 3 + 1) * 64 + rl) * 4 + rr];
            pv += pp[((wv * 3 + 2) * 64 + rl) * 4 + rr];
        }

        // ---- gates + state update ----
        float fg = sigmoidf_(pf);
        float ig = sigmoidf_(pu);
        float gg = tanhf_(pv);
        p1s = fg * p1s + ig * gg;
        float p2 = sigmoidf_(xio) * tanhf_(p1s);

        if (t < S_ - 1) {
            float xin = embn + p2;
            xio = xin;
            publish((t + 1) & 1, e0 + (unsigned)t + 2u, xin);
            __builtin_nontemporal_store(p2, &out[(b * S_ + t) * H_ + j]);
            if (t + 2 < S_) embn = emb[(b * S_ + t + 2) * H_ + j];
        } else {
            __builtin_nontemporal_store(p2, &out[(b * S_ + t) * H_ + j]);
        }
    }
}

extern "C" void kernel_launch(void* const* d_in, const int* in_sizes, int n_in,
                              void* d_out, int out_size, void* d_ws, size_t ws_size,
                              hipStream_t stream)
{
    const float* emb = (const float*)d_in[0];
    const float* W   = (const float*)d_in[1];
    const float* bWv = (const float*)d_in[2];
    const float* U   = (const float*)d_in[3];
    const float* bUv = (const float*)d_in[4];
    const float* V   = (const float*)d_in[5];
    const float* bVv = (const float*)d_in[6];
    float* outp = (float*)d_out;
    unsigned char* ws = (unsigned char*)d_ws;
    (void)in_sizes; (void)n_in; (void)out_size; (void)ws_size;

    void* args[] = {(void*)&emb, (void*)&W, (void*)&bWv, (void*)&U, (void*)&bUv,
                    (void*)&V, (void*)&bVv, (void*)&outp, (void*)&ws};
    hipError_t err = hipLaunchCooperativeKernel((const void*)lstm_scan,
                                                dim3(256), dim3(256), args, 0, stream);
    if (err != hipSuccess) {
        lstm_scan<<<dim3(256), dim3(256), 0, stream>>>(emb, W, bWv, U, bUv, V, bVv, outp, ws);
    }
}

// Round 23
// 1659.302 us; speedup vs baseline: 1.5404x; 1.5404x over previous
//
#include <hip/hip_runtime.h>

typedef _Float16 half8 __attribute__((ext_vector_type(8)));
typedef float floatx4 __attribute__((ext_vector_type(4)));
typedef unsigned int uintx4 __attribute__((ext_vector_type(4)));
typedef unsigned long long u64t;

#define B_ 64
#define S_ 512
#define H_ 1024

// Per-wave subslots: ONE padded 64B line per publisher block; words 0..3 are
// the 4 waves' counters (rest padding). .bss, zero at load. Monotonic: each
// subslot advances by exactly S_ per launch; all 4 equal at quiescence.
// Per-launch base e0 = own line word 0, read before any arrival.
__device__ unsigned slotL[4][64][16];

__device__ __forceinline__ float sigmoidf_(float x) { return 1.0f / (1.0f + __expf(-x)); }
__device__ __forceinline__ float tanhf_(float x) {
    return 1.0f - 2.0f / (__expf(2.0f * x) + 1.0f);   // saturates correctly via __expf
}

// 256 blocks x 256 threads -- r21 VERBATIM (best: 1.555 ms) except:
//  1. BARRIER-FREE publish: wave w's payload rows (4w..4w+3) are ITS OWN
//     stores; after the wave-level vmcnt(0) drain, lane0-of-wave raises
//     subslot word w on the block's padded line. No __syncthreads, no
//     tid0-only serialization on the publish path (r21 paid a cross-wave
//     join + single-storer leg every step).
//  2. consumer polls the SAME one line: two 8B loads cover all 4 subslots
//     (gates on min >= tgt) -- identical retry cost class as r21.
//  3. backoff s_sleep(2) (was 4) -- halves detect quantization.
// r22's drain removal is REVERTED (drain-before-notify proven load-bearing).
//
// Geometry: block (cb=bid&63, mb=bid>>6) owns the 16x16 tile: batches
// [16mb,16mb+16) x cols [16cb,16cb+16), full K=1024; wave = K-quarter;
// K-reduce in double-buffered LDS (ONE reduce-__syncthreads per step);
// payload read = 8 forced asm dwordx4 sc1 (single burst, read once).
//
// WAR safety: X publishes buf[(t+1)&1] only after X's reduce-sync(t), which
// joins all 4 X-waves' polls(t) (source union = all 64 blocks). Poll(t)
// passing proves ALL 4 subslots of every source P reached e0+t+1, i.e.
// every P-wave drained its step-t payload, which follows P's reduce-sync
// (t-1), which joins P's reads of buf[(t-1)&1] == buf[(t+1)&1]. Safe.
__global__ void __launch_bounds__(256, 1)
lstm_scan(const float* __restrict__ emb, const float* __restrict__ W, const float* __restrict__ bW,
          const float* __restrict__ U, const float* __restrict__ bU,
          const float* __restrict__ V, const float* __restrict__ bV,
          float* __restrict__ out, unsigned char* __restrict__ ws)
{
    const int bid  = blockIdx.x;
    const int cb   = bid & 63;    // column group (16 H-cols)
    const int mb   = bid >> 6;    // batch group (16 batches)
    const int tid  = threadIdx.x;
    const int w    = tid >> 6;    // wave id = K-quarter AND publisher wave
    const int lane = tid & 63;
    const int fr   = lane & 15;   // A-frag row index
    const int kg   = lane >> 4;   // A-frag k-block

    u64t* pub  = (u64t*)ws;       // [2][64 rows][256 words] 4 f16/word = 256 KB
    char* pubc = (char*)ws;

    __shared__ __align__(16) float part[2][4 * 3 * 64 * 4];   // 2 x 12 KB

    const unsigned e0 = __hip_atomic_load(&slotL[mb][cb][0], __ATOMIC_RELAXED,
                                          __HIP_MEMORY_SCOPE_AGENT);

    // ---- persistent weight fragments (f16, registers): 3 gates x 8 ksteps ----
    // B-frag of mfma_f32_16x16x32_f16: lane l holds B[k=(l>>4)*8+e][n=l&15],
    // B[k][n] = Wgate[16*cb + n][k].  (Layout proven rounds 1/4-21.)
    half8 Bf[3][8];
    {
        const int jrow = cb * 16 + fr;
        const int kb   = w * 256 + kg * 8;
        const float* p0 = W + jrow * H_ + kb;
        const float* p1 = U + jrow * H_ + kb;
        const float* p2 = V + jrow * H_ + kb;
        #pragma unroll
        for (int ks = 0; ks < 8; ++ks) {
            half8 h0, h1, h2;
            #pragma unroll
            for (int e = 0; e < 8; ++e) {
                h0[e] = (_Float16)p0[ks * 32 + e];
                h1[e] = (_Float16)p1[ks * 32 + e];
                h2[e] = (_Float16)p2[ks * 32 + e];
            }
            Bf[0][ks] = h0; Bf[1][ks] = h1; Bf[2][ks] = h2;
        }
    }

    // ---- elementwise ownership: thread -> ONE cell (b, j) ----
    // wave w owns rows rt = 4w..4w+3, so its payload stores are its own.
    const int rt = tid >> 4;
    const int ct = tid & 15;
    const int b  = mb * 16 + rt;
    const int j  = cb * 16 + ct;
    const float bw = bW[j], bu = bU[j], bv = bV[j];
    const int rl = (rt >> 2) * 16 + ct;   // C/D source lane (proven)
    const int rr = rt & 3;                // C/D source reg

    // barrier-free publish: pack 4 f16 into one 8B sc1 word (ct&3==0 lanes),
    // drain THIS WAVE's stores, raise THIS WAVE's subslot. No __syncthreads.
    auto publish = [&](int buf, unsigned slotval, float xin) {
        union { _Float16 h; unsigned short u; } cvp; cvp.h = (_Float16)xin;
        unsigned mine = cvp.u;
        unsigned lo = mine | ((unsigned)__shfl_xor((int)mine, 1) << 16);
        unsigned hi = (unsigned)__shfl_xor((int)lo, 2);
        if ((ct & 3) == 0)
            __hip_atomic_store(&pub[(unsigned)(buf * 16384 + b * 256 + cb * 4 + (ct >> 2))],
                               (u64t)lo | ((u64t)hi << 32),
                               __ATOMIC_RELAXED, __HIP_MEMORY_SCOPE_AGENT);
        asm volatile("s_waitcnt vmcnt(0)" ::: "memory");  // this wave's payload acked
        if (lane == 0)
            __hip_atomic_store(&slotL[mb][cb][w], slotval, __ATOMIC_RELAXED,
                               __HIP_MEMORY_SCOPE_AGENT);
    };

    // quarter poll: all lanes poll source (lane&15) of this wave's 16
    // sources; two 8B loads cover the line's 4 subslots; gate on min.
    auto waitq = [&](unsigned tgt) {
        const u64t* line = (const u64t*)&slotL[mb][w * 16 + (lane & 15)][0];
        for (;;) {
            u64t v01 = __hip_atomic_load(&line[0], __ATOMIC_RELAXED, __HIP_MEMORY_SCOPE_AGENT);
            u64t v23 = __hip_atomic_load(&line[1], __ATOMIC_RELAXED, __HIP_MEMORY_SCOPE_AGENT);
            unsigned s0 = (unsigned)v01, s1 = (unsigned)(v01 >> 32);
            unsigned s2 = (unsigned)v23, s3 = (unsigned)(v23 >> 32);
            bool ok = ((int)(s0 - tgt) >= 0) & ((int)(s1 - tgt) >= 0)
                    & ((int)(s2 - tgt) >= 0) & ((int)(s3 - tgt) >= 0);
            if (__all(ok)) break;
            __builtin_amdgcn_s_sleep(2);   // ~0.06us backoff
        }
        asm volatile("" ::: "memory");
    };

    float p1s = 0.0f;
    float xio = emb[(b * S_ + 0) * H_ + j];    // p2 init = 0
    publish(0, e0 + 1u, xio);
    float embn = emb[(b * S_ + 1) * H_ + j];   // prefetch t=1 (compiler-managed)

    for (int t = 0; t < S_; ++t) {
        waitq(e0 + (unsigned)t + 1u);

        // ---- payload burst: 8 forced dwordx4 sc1 (one round-trip) [r21] ----
        const char* base = pubc + (unsigned)(((t & 1) * 64 + mb * 16 + fr) * 2048
                                             + w * 512 + kg * 16);
        uintx4 q0, q1, q2, q3, q4, q5, q6, q7;
        asm volatile("global_load_dwordx4 %0, %1, off sc1"            : "=v"(q0) : "v"(base));
        asm volatile("global_load_dwordx4 %0, %1, off offset:64 sc1"  : "=v"(q1) : "v"(base));
        asm volatile("global_load_dwordx4 %0, %1, off offset:128 sc1" : "=v"(q2) : "v"(base));
        asm volatile("global_load_dwordx4 %0, %1, off offset:192 sc1" : "=v"(q3) : "v"(base));
        asm volatile("global_load_dwordx4 %0, %1, off offset:256 sc1" : "=v"(q4) : "v"(base));
        asm volatile("global_load_dwordx4 %0, %1, off offset:320 sc1" : "=v"(q5) : "v"(base));
        asm volatile("global_load_dwordx4 %0, %1, off offset:384 sc1" : "=v"(q6) : "v"(base));
        asm volatile("global_load_dwordx4 %0, %1, off offset:448 sc1" : "=v"(q7) : "v"(base));
        asm volatile("s_waitcnt vmcnt(0)" ::: "memory");
        __builtin_amdgcn_sched_barrier(0);   // rule #18: results usable below

        // ---- MFMA from captured registers [r21] ----
        floatx4 a0 = {0.f, 0.f, 0.f, 0.f};
        floatx4 a1 = {0.f, 0.f, 0.f, 0.f};
        floatx4 a2 = {0.f, 0.f, 0.f, 0.f};
        union { uintx4 v; half8 h; } cva;
        #define DO_KS(ks, Q)                                                          \
        {                                                                             \
            cva.v = Q; half8 Af = cva.h;                                              \
            a0 = __builtin_amdgcn_mfma_f32_16x16x32_f16(Af, Bf[0][ks], a0, 0, 0, 0);  \
            a1 = __builtin_amdgcn_mfma_f32_16x16x32_f16(Af, Bf[1][ks], a1, 0, 0, 0);  \
            a2 = __builtin_amdgcn_mfma_f32_16x16x32_f16(Af, Bf[2][ks], a2, 0, 0, 0);  \
        }
        DO_KS(0, q0) DO_KS(1, q1) DO_KS(2, q2) DO_KS(3, q3)
        DO_KS(4, q4) DO_KS(5, q5) DO_KS(6, q6) DO_KS(7, q7)
        #undef DO_KS

        // ---- K-reduction in LDS (double-buffered, one sync) [r21] ----
        float* pp = part[t & 1];
        *(floatx4*)&pp[((w * 3 + 0) * 64 + lane) * 4] = a0;
        *(floatx4*)&pp[((w * 3 + 1) * 64 + lane) * 4] = a1;
        *(floatx4*)&pp[((w * 3 + 2) * 64 + lane) * 4] = a2;
        __syncthreads();

        float pf = bw, pu = bu, pv = bv;
        #pragma unroll
        for (int wv = 0; wv < 4; ++wv) {
            pf += pp[((wv * 3 + 0) * 64 + rl) * 4 + rr];
            pu += pp[((wv * 3 + 1) * 64 + rl) * 4 + rr];
            pv += pp[((wv * 3 + 2) * 64 + rl) * 4 + rr];
        }

        // ---- gates + state update [r21] ----
        float fg = sigmoidf_(pf);
        float ig = sigmoidf_(pu);
        float gg = tanhf_(pv);
        p1s = fg * p1s + ig * gg;
        float p2 = sigmoidf_(xio) * tanhf_(p1s);

        if (t < S_ - 1) {
            float xin = embn + p2;
            xio = xin;
            publish((t + 1) & 1, e0 + (unsigned)t + 2u, xin);
            // after the subslot store: these drain during other blocks' polls
            __builtin_nontemporal_store(p2, &out[(b * S_ + t) * H_ + j]);
            if (t + 2 < S_) embn = emb[(b * S_ + t + 2) * H_ + j];
        } else {
            __builtin_nontemporal_store(p2, &out[(b * S_ + t) * H_ + j]);
        }
    }
}

extern "C" void kernel_launch(void* const* d_in, const int* in_sizes, int n_in,
                              void* d_out, int out_size, void* d_ws, size_t ws_size,
                              hipStream_t stream)
{
    const float* emb = (const float*)d_in[0];
    const float* W   = (const float*)d_in[1];
    const float* bWv = (const float*)d_in[2];
    const float* U   = (const float*)d_in[3];
    const float* bUv = (const float*)d_in[4];
    const float* V   = (const float*)d_in[5];
    const float* bVv = (const float*)d_in[6];
    float* outp = (float*)d_out;
    unsigned char* ws = (unsigned char*)d_ws;
    (void)in_sizes; (void)n_in; (void)out_size; (void)ws_size;

    void* args[] = {(void*)&emb, (void*)&W, (void*)&bWv, (void*)&U, (void*)&bUv,
                    (void*)&V, (void*)&bVv, (void*)&outp, (void*)&ws};
    hipError_t err = hipLaunchCooperativeKernel((const void*)lstm_scan,
                                                dim3(256), dim3(256), args, 0, stream);
    if (err != hipSuccess) {
        lstm_scan<<<dim3(256), dim3(256), 0, stream>>>(emb, W, bWv, U, bUv, V, bVv, outp, ws);
    }
}

// Round 24
// 1561.927 us; speedup vs baseline: 1.6364x; 1.0623x over previous
//
#include <hip/hip_runtime.h>

typedef _Float16 half8 __attribute__((ext_vector_type(8)));
typedef float floatx4 __attribute__((ext_vector_type(4)));
typedef unsigned int uintx4 __attribute__((ext_vector_type(4)));
typedef unsigned long long u64t;

#define B_ 64
#define S_ 512
#define H_ 1024

// Arrival slots, padded to one 64B line each (r17-proven: kills poll-line
// contention). .bss: zero at load, untouched by ws poison. Monotonic: each
// block's slot advances by exactly S_ per launch. Per-launch base e0 = own
// slot value read before any arrival.
__device__ unsigned slotP[4][64][16];

__device__ __forceinline__ float sigmoidf_(float x) { return 1.0f / (1.0f + __expf(-x)); }
__device__ __forceinline__ float tanhf_(float x) {
    return 1.0f - 2.0f / (__expf(2.0f * x) + 1.0f);   // saturates correctly via __expf
}

// 256 blocks x 256 threads -- the session-best structure (r21, 1554.8 us):
// r17's padded-slot protocol + per-wave quarter polls + s_sleep(4) backoff.
// Block (cb=bid&63, mb=bid>>6) owns the 16x16 tile: batches [16mb,16mb+16)
// x cols [16cb,16cb+16), full K=1024; wave = K-quarter; K-reduce in
// double-buffered LDS (one reduce-__syncthreads per step); publish = packed
// 8B sc1 payload stores -> vmcnt(0) drain -> __syncthreads -> tid0 slot
// store; payload read = 8 forced asm dwordx4 sc1 (single burst, read once).
//
// Protocol findings locked in across r14-r23:
//  - drain-before-notify is load-bearing (r22: removing it -> re-burst storm)
//  - tags-with-data lose to slots (r12/r19: 1.5-2x broadcast bytes + retries)
//  - slot padding + single-poller + backoff was the -30% lever (r17)
//  - per-wave subslots / XCD mirrors / housekeeping batching: neutral-worse
//
// WAR safety: publish(t+1) by X follows X's reduce-sync(t), which joins all
// 4 waves' polls(t) (source union = all 64 blocks) and all reads of
// buf[(t-1)&1]; poll(t) passing proves all 64 sources published t, i.e.
// finished THEIR buf[(t-1)&1] reads. Overwriting buf[(t+1)&1] is safe.
__global__ void __launch_bounds__(256, 1)
lstm_scan(const float* __restrict__ emb, const float* __restrict__ W, const float* __restrict__ bW,
          const float* __restrict__ U, const float* __restrict__ bU,
          const float* __restrict__ V, const float* __restrict__ bV,
          float* __restrict__ out, unsigned char* __restrict__ ws)
{
    const int bid  = blockIdx.x;
    const int cb   = bid & 63;    // column group (16 H-cols)
    const int mb   = bid >> 6;    // batch group (16 batches)
    const int tid  = threadIdx.x;
    const int w    = tid >> 6;    // wave id = K-quarter
    const int lane = tid & 63;
    const int fr   = lane & 15;   // A-frag row index
    const int kg   = lane >> 4;   // A-frag k-block

    u64t* pub  = (u64t*)ws;       // [2][64 rows][256 words] 4 f16/word = 256 KB
    char* pubc = (char*)ws;

    __shared__ __align__(16) float part[2][4 * 3 * 64 * 4];   // 2 x 12 KB

    const unsigned e0 = __hip_atomic_load(&slotP[mb][cb][0], __ATOMIC_RELAXED,
                                          __HIP_MEMORY_SCOPE_AGENT);

    // ---- persistent weight fragments (f16, registers): 3 gates x 8 ksteps ----
    // B-frag of mfma_f32_16x16x32_f16: lane l holds B[k=(l>>4)*8+e][n=l&15],
    // B[k][n] = Wgate[16*cb + n][k].  (Layout proven rounds 1/4-23.)
    half8 Bf[3][8];
    {
        const int jrow = cb * 16 + fr;
        const int kb   = w * 256 + kg * 8;
        const float* p0 = W + jrow * H_ + kb;
        const float* p1 = U + jrow * H_ + kb;
        const float* p2 = V + jrow * H_ + kb;
        #pragma unroll
        for (int ks = 0; ks < 8; ++ks) {
            half8 h0, h1, h2;
            #pragma unroll
            for (int e = 0; e < 8; ++e) {
                h0[e] = (_Float16)p0[ks * 32 + e];
                h1[e] = (_Float16)p1[ks * 32 + e];
                h2[e] = (_Float16)p2[ks * 32 + e];
            }
            Bf[0][ks] = h0; Bf[1][ks] = h1; Bf[2][ks] = h2;
        }
    }

    // ---- elementwise ownership: thread -> ONE cell (b, j) ----
    const int rt = tid >> 4;
    const int ct = tid & 15;
    const int b  = mb * 16 + rt;
    const int j  = cb * 16 + ct;
    const float bw = bW[j], bu = bU[j], bv = bV[j];
    const int rl = (rt >> 2) * 16 + ct;   // C/D source lane (proven)
    const int rr = rt & 3;                // C/D source reg

    // publish: pack 4 f16 into one 8B sc1 word, drain, join waves, tid0
    // raises the block slot.
    auto publish = [&](int buf, unsigned slotval, float xin) {
        union { _Float16 h; unsigned short u; } cvp; cvp.h = (_Float16)xin;
        unsigned mine = cvp.u;
        unsigned lo = mine | ((unsigned)__shfl_xor((int)mine, 1) << 16);
        unsigned hi = (unsigned)__shfl_xor((int)lo, 2);
        if ((ct & 3) == 0)
            __hip_atomic_store(&pub[(unsigned)(buf * 16384 + b * 256 + cb * 4 + (ct >> 2))],
                               (u64t)lo | ((u64t)hi << 32),
                               __ATOMIC_RELAXED, __HIP_MEMORY_SCOPE_AGENT);
        asm volatile("s_waitcnt vmcnt(0)" ::: "memory");  // payload acked at LLC
        __syncthreads();
        if (tid == 0)
            __hip_atomic_store(&slotP[mb][cb][0], slotval, __ATOMIC_RELAXED,
                               __HIP_MEMORY_SCOPE_AGENT);
    };

    // per-wave quarter poll: lanes 0..15 poll the wave's 16 source blocks
    // (64B-padded lines, 1 load/slot/retry); __all exits the wave together.
    auto waitq = [&](unsigned tgt) {
        for (;;) {
            unsigned v = tgt;
            if (lane < 16)
                v = __hip_atomic_load(&slotP[mb][w * 16 + lane][0], __ATOMIC_RELAXED,
                                      __HIP_MEMORY_SCOPE_AGENT);
            if (__all((int)(v - tgt) >= 0)) break;
            __builtin_amdgcn_s_sleep(4);   // ~0.1us backoff
        }
        asm volatile("" ::: "memory");
    };

    float p1s = 0.0f;
    float xio = emb[(b * S_ + 0) * H_ + j];    // p2 init = 0
    publish(0, e0 + 1u, xio);
    float embn = emb[(b * S_ + 1) * H_ + j];   // prefetch t=1 (compiler-managed)

    for (int t = 0; t < S_; ++t) {
        waitq(e0 + (unsigned)t + 1u);

        // ---- payload burst: 8 forced dwordx4 sc1 (one round-trip) ----
        const char* base = pubc + (unsigned)(((t & 1) * 64 + mb * 16 + fr) * 2048
                                             + w * 512 + kg * 16);
        uintx4 q0, q1, q2, q3, q4, q5, q6, q7;
        asm volatile("global_load_dwordx4 %0, %1, off sc1"            : "=v"(q0) : "v"(base));
        asm volatile("global_load_dwordx4 %0, %1, off offset:64 sc1"  : "=v"(q1) : "v"(base));
        asm volatile("global_load_dwordx4 %0, %1, off offset:128 sc1" : "=v"(q2) : "v"(base));
        asm volatile("global_load_dwordx4 %0, %1, off offset:192 sc1" : "=v"(q3) : "v"(base));
        asm volatile("global_load_dwordx4 %0, %1, off offset:256 sc1" : "=v"(q4) : "v"(base));
        asm volatile("global_load_dwordx4 %0, %1, off offset:320 sc1" : "=v"(q5) : "v"(base));
        asm volatile("global_load_dwordx4 %0, %1, off offset:384 sc1" : "=v"(q6) : "v"(base));
        asm volatile("global_load_dwordx4 %0, %1, off offset:448 sc1" : "=v"(q7) : "v"(base));
        asm volatile("s_waitcnt vmcnt(0)" ::: "memory");
        __builtin_amdgcn_sched_barrier(0);   // rule #18: results usable below

        // ---- MFMA from captured registers ----
        floatx4 a0 = {0.f, 0.f, 0.f, 0.f};
        floatx4 a1 = {0.f, 0.f, 0.f, 0.f};
        floatx4 a2 = {0.f, 0.f, 0.f, 0.f};
        union { uintx4 v; half8 h; } cva;
        #define DO_KS(ks, Q)                                                          \
        {                                                                             \
            cva.v = Q; half8 Af = cva.h;                                              \
            a0 = __builtin_amdgcn_mfma_f32_16x16x32_f16(Af, Bf[0][ks], a0, 0, 0, 0);  \
            a1 = __builtin_amdgcn_mfma_f32_16x16x32_f16(Af, Bf[1][ks], a1, 0, 0, 0);  \
            a2 = __builtin_amdgcn_mfma_f32_16x16x32_f16(Af, Bf[2][ks], a2, 0, 0, 0);  \
        }
        DO_KS(0, q0) DO_KS(1, q1) DO_KS(2, q2) DO_KS(3, q3)
        DO_KS(4, q4) DO_KS(5, q5) DO_KS(6, q6) DO_KS(7, q7)
        #undef DO_KS

        // ---- K-reduction in LDS (double-buffered, one sync) ----
        float* pp = part[t & 1];
        *(floatx4*)&pp[((w * 3 + 0) * 64 + lane) * 4] = a0;
        *(floatx4*)&pp[((w * 3 + 1) * 64 + lane) * 4] = a1;
        *(floatx4*)&pp[((w * 3 + 2) * 64 + lane) * 4] = a2;
        __syncthreads();

        float pf = bw, pu = bu, pv = bv;
        #pragma unroll
        for (int wv = 0; wv < 4; ++wv) {
            pf += pp[((wv * 3 + 0) * 64 + rl) * 4 + rr];
            pu += pp[((wv * 3 + 1) * 64 + rl) * 4 + rr];
            pv += pp[((wv * 3 + 2) * 64 + rl) * 4 + rr];
        }

        // ---- gates + state update ----
        float fg = sigmoidf_(pf);
        float ig = sigmoidf_(pu);
        float gg = tanhf_(pv);
        p1s = fg * p1s + ig * gg;
        float p2 = sigmoidf_(xio) * tanhf_(p1s);

        if (t < S_ - 1) {
            float xin = embn + p2;
            xio = xin;
            publish((t + 1) & 1, e0 + (unsigned)t + 2u, xin);
            // after the slot store: these drain during other blocks' polls
            __builtin_nontemporal_store(p2, &out[(b * S_ + t) * H_ + j]);
            if (t + 2 < S_) embn = emb[(b * S_ + t + 2) * H_ + j];
        } else {
            __builtin_nontemporal_store(p2, &out[(b * S_ + t) * H_ + j]);
        }
    }
}

extern "C" void kernel_launch(void* const* d_in, const int* in_sizes, int n_in,
                              void* d_out, int out_size, void* d_ws, size_t ws_size,
                              hipStream_t stream)
{
    const float* emb = (const float*)d_in[0];
    const float* W   = (const float*)d_in[1];
    const float* bWv = (const float*)d_in[2];
    const float* U   = (const float*)d_in[3];
    const float* bUv = (const float*)d_in[4];
    const float* V   = (const float*)d_in[5];
    const float* bVv = (const float*)d_in[6];
    float* outp = (float*)d_out;
    unsigned char* ws = (unsigned char*)d_ws;
    (void)in_sizes; (void)n_in; (void)out_size; (void)ws_size;

    void* args[] = {(void*)&emb, (void*)&W, (void*)&bWv, (void*)&U, (void*)&bUv,
                    (void*)&V, (void*)&bVv, (void*)&outp, (void*)&ws};
    hipError_t err = hipLaunchCooperativeKernel((const void*)lstm_scan,
                                                dim3(256), dim3(256), args, 0, stream);
    if (err != hipSuccess) {
        lstm_scan<<<dim3(256), dim3(256), 0, stream>>>(emb, W, bWv, U, bUv, V, bVv, outp, ws);
    }
}